// Round 2
// baseline (560.580 us; speedup 1.0000x reference)
//
#include <hip/hip_runtime.h>
#include <hip/hip_bf16.h>

#define BATCH 8
#define CH    64
#define CH2   32
#define NN    4096
#define BN    (BATCH * NN)   // 32768 rows total
#define KPAD  72             // LDS key-tile row stride (elements)
#define VPAD  72             // LDS value-tile row stride (elements)
#define YPAD  36             // flash epilogue transpose row stride (floats)
#define RPAD  40             // reduce_proj LDS row stride (bf16 elements, 16B-aligned)
#define MAXSPLIT 8

typedef __attribute__((ext_vector_type(8)))  short        short8;    // 8 bf16 (MFMA A/B frag)
typedef __attribute__((ext_vector_type(4)))  float        floatx4;   // 16x16 MFMA C/D frag
typedef __attribute__((ext_vector_type(16))) float        floatx16;  // 32x32 MFMA C/D frag
typedef __attribute__((ext_vector_type(4)))  unsigned int uint4v;
typedef __attribute__((ext_vector_type(8)))  unsigned short ushort8v;
typedef unsigned short ushort_t;

#define LOG2E      1.4426950408889634f
#define SQRT_LOG2E 1.2011224087864498f   // sqrt(log2(e)); Q,K both scaled -> S in log2 units

__device__ __forceinline__ unsigned short f2bf_rne(float f) {
    unsigned int u = __float_as_uint(f);
    return (unsigned short)((u + 0x7FFFu + ((u >> 16) & 1u)) >> 16);
}

// ---- fused prep (unchanged from R8)
__global__ __launch_bounds__(256) void prep_fused(const float* __restrict__ x,
                                                  const float* __restrict__ gw,
                                                  const float* __restrict__ gb,
                                                  ushort_t* __restrict__ xT,
                                                  float* __restrict__ mlog,
                                                  ushort_t* __restrict__ gxT) {
    __shared__ float gwl[CH2 * CH];   // [o][c]
    __shared__ float gbl[CH2];
    int t = threadIdx.x;
    for (int i = t; i < CH2 * CH; i += 256) gwl[i] = gw[i];
    if (t < CH2) gbl[t] = gb[t];
    __syncthreads();

    int g   = blockIdx.x * 256 + t;
    int row = g >> 2;
    int q4  = g & 3;
    int b = row >> 12, n = row & (NN - 1);
    const float* xp = x + (size_t)b * CH * NN + n;

    float xv[16];
    #pragma unroll
    for (int j = 0; j < 16; ++j) xv[j] = xp[(size_t)(q4 * 16 + j) * NN];

    float ns = 0.f;
    short8 v0, v1;
    #pragma unroll
    for (int j = 0; j < 8; ++j) {
        ns += xv[j] * xv[j];
        v0[j] = (short)f2bf_rne(xv[j] * SQRT_LOG2E);
    }
    #pragma unroll
    for (int j = 0; j < 8; ++j) {
        ns += xv[8 + j] * xv[8 + j];
        v1[j] = (short)f2bf_rne(xv[8 + j] * SQRT_LOG2E);
    }
    *(short8*)(xT + (size_t)row * CH + q4 * 16)     = v0;
    *(short8*)(xT + (size_t)row * CH + q4 * 16 + 8) = v1;
    ns += __shfl_xor(ns, 1);
    ns += __shfl_xor(ns, 2);
    if (q4 == 0) mlog[row] = 12.0f * sqrtf(ns) * LOG2E;

    float acc[CH2];
    #pragma unroll
    for (int o = 0; o < CH2; ++o) {
        const float4* wr = (const float4*)(gwl + o * CH + q4 * 16);
        float4 w0 = wr[0], w1 = wr[1], w2 = wr[2], w3 = wr[3];
        float a;
        a  = w0.x * xv[0]  + w0.y * xv[1]  + w0.z * xv[2]  + w0.w * xv[3];
        a += w1.x * xv[4]  + w1.y * xv[5]  + w1.z * xv[6]  + w1.w * xv[7];
        a += w2.x * xv[8]  + w2.y * xv[9]  + w2.z * xv[10] + w2.w * xv[11];
        a += w3.x * xv[12] + w3.y * xv[13] + w3.z * xv[14] + w3.w * xv[15];
        acc[o] = a;
    }
    #pragma unroll
    for (int o = 0; o < CH2; ++o) {
        acc[o] += __shfl_xor(acc[o], 1);
        acc[o] += __shfl_xor(acc[o], 2);
    }
    #pragma unroll
    for (int i = 0; i < 8; ++i) {
        int o = q4 * 8 + i;
        gxT[((size_t)b * CH2 + o) * NN + n] = f2bf_rne(acc[o] + gbl[o]);
    }
}

// ---- flash attention, S^T formulation (32x32x16 MFMA).
// R9: occupancy attack. split=8 -> grid 2048 = 8 blocks/CU of work; single
// K/V LDS buffer (18432 B incl. epilogue alias) -> 8 blocks resident;
// __launch_bounds__(256,8) pins VGPR<=64 -> 32 waves/CU (was 16 max, 31% meas).
// Inner loop slimmed: v_cvt_pk_bf16_f32 packs P pairs (1 op vs 3), and the
// lane^32 butterfly is 2x v_permlane32_swap_b32 (VALU) instead of
// 4x ds_bpermute + 4x cndmask per fragment.
__global__ __launch_bounds__(256, 8) void flash_attn(const ushort_t* __restrict__ xT,
                                                     const ushort_t* __restrict__ gxT,
                                                     const float* __restrict__ mlog,
                                                     ushort_t* __restrict__ py,
                                                     float* __restrict__ pl,
                                                     int ksplit) {
    __shared__ __align__(16) unsigned char smem[18432];
    ushort_t* Klds = (ushort_t*)smem;               // 64 x KPAD bf16 (9216 B)
    ushort_t* Vlds = Klds + 64 * KPAD;              // 32 x VPAD bf16 (4608 B)

    const int tid = threadIdx.x, wave = tid >> 6, lane = tid & 63;
    const int q5 = lane & 31;
    const int h  = lane >> 5;
    const int bq = blockIdx.x & 255;
    const int sp = blockIdx.x >> 8;
    const int b = bq >> 5, qt = bq & 31;
    const int n0 = qt * 128 + wave * 32;
    const int k0 = sp * ksplit;

    short8 qf[4];
    {
        const ushort_t* qp = xT + ((size_t)(b * NN + n0 + q5)) * CH + h * 8;
        #pragma unroll
        for (int f = 0; f < 4; ++f) qf[f] = *(const short8*)(qp + f * 16);
    }
    const float ml = mlog[(size_t)b * NN + n0 + q5];

    short8 ones;
    #pragma unroll
    for (int j = 0; j < 8; ++j) ones[j] = (short)0x3F80;   // bf16 1.0

    floatx16 yt, lt;
    #pragma unroll
    for (int i = 0; i < 16; ++i) { yt[i] = 0.f; lt[i] = 0.f; }

    const ushort_t* kb = xT + (size_t)(b * NN + k0) * CH;
    const ushort_t* vb = gxT + (size_t)b * CH2 * NN + k0;
    const int iters = ksplit >> 6;
    const int skey = tid >> 3, sc0 = (tid & 7) * 8;   // K rows 0..31(+32), V och 0..31

    // prologue: stage tile 0
    {
        short8 k0r = *(const short8*)(kb + (size_t)skey * CH + sc0);
        short8 k1r = *(const short8*)(kb + (size_t)(skey + 32) * CH + sc0);
        short8 v0r = *(const short8*)(vb + (size_t)skey * NN + sc0);
        *(short8*)(&Klds[skey * KPAD + sc0])        = k0r;
        *(short8*)(&Klds[(skey + 32) * KPAD + sc0]) = k1r;
        *(short8*)(&Vlds[skey * VPAD + sc0])        = v0r;
    }
    __syncthreads();

    for (int kt = 0; kt < iters; ++kt) {
        // prefetch tile kt+1 into registers (clamped; redundant on last iter)
        const int kp = (kt + 1 < iters) ? (kt + 1) : kt;
        const size_t kof = (size_t)kp << 12;
        short8 nk0 = *(const short8*)(kb + kof + (size_t)skey * CH + sc0);
        short8 nk1 = *(const short8*)(kb + kof + (size_t)(skey + 32) * CH + sc0);
        short8 nv  = *(const short8*)(vb + (size_t)skey * NN + kp * 64 + sc0);

        short8 vf[4];
        #pragma unroll
        for (int fr = 0; fr < 4; ++fr)
            vf[fr] = *(const short8*)(&Vlds[q5 * VPAD + fr * 16 + h * 8]);

        #pragma unroll
        for (int T = 0; T < 2; ++T) {
            floatx16 st;
            #pragma unroll
            for (int i = 0; i < 16; ++i) st[i] = -ml;    // softmax shift folded into C-init
            __builtin_amdgcn_s_setprio(1);
            #pragma unroll
            for (int f = 0; f < 4; ++f) {
                short8 kf = *(const short8*)(&Klds[(T * 32 + q5) * KPAD + f * 16 + h * 8]);
                st = __builtin_amdgcn_mfma_f32_32x32x16_bf16(kf, qf[f], st, 0, 0, 0);
            }
            __builtin_amdgcn_s_setprio(0);
            // P = exp2(st); pack pairs to bf16 RNE in one op each
            unsigned int d[8];
            #pragma unroll
            for (int r2 = 0; r2 < 8; ++r2) {
                float p0 = __builtin_amdgcn_exp2f(st[2 * r2]);
                float p1 = __builtin_amdgcn_exp2f(st[2 * r2 + 1]);
                unsigned int pk;
                asm("v_cvt_pk_bf16_f32 %0, %1, %2" : "=v"(pk) : "v"(p0), "v"(p1));
                d[r2] = pk;
            }
            // P^T B-frags: lane^32 exchange via permlane32_swap
            //   swap(a,b): a' = h? b_partner : a_self ; b' = h? b_self : a_partner
            #pragma unroll
            for (int fp = 0; fp < 2; ++fp) {
                unsigned int b0 = d[fp * 4 + 0], b1 = d[fp * 4 + 1];
                unsigned int b2 = d[fp * 4 + 2], b3 = d[fp * 4 + 3];
                asm("v_permlane32_swap_b32 %0, %1" : "+v"(b0), "+v"(b2));
                asm("v_permlane32_swap_b32 %0, %1" : "+v"(b1), "+v"(b3));
                uint4v bv;
                bv[0] = b0; bv[1] = b1; bv[2] = b2; bv[3] = b3;
                short8 pb = __builtin_bit_cast(short8, bv);
                __builtin_amdgcn_s_setprio(1);
                yt = __builtin_amdgcn_mfma_f32_32x32x16_bf16(vf[T * 2 + fp], pb, yt, 0, 0, 0);
                lt = __builtin_amdgcn_mfma_f32_32x32x16_bf16(ones, pb, lt, 0, 0, 0);
                __builtin_amdgcn_s_setprio(0);
            }
        }

        __syncthreads();                     // all waves done reading tile kt
        if (kt + 1 < iters) {
            *(short8*)(&Klds[skey * KPAD + sc0])        = nk0;
            *(short8*)(&Klds[(skey + 32) * KPAD + sc0]) = nk1;
            *(short8*)(&Vlds[skey * VPAD + sc0])        = nv;
            __syncthreads();                 // publish tile kt+1
        }
    }

    // epilogue: transpose y^T via LDS (aliases K/V buffer; reads all drained)
    float* yb = (float*)smem + wave * 32 * YPAD;
    #pragma unroll
    for (int reg = 0; reg < 16; ++reg) {
        int o = (reg & 3) + 8 * (reg >> 2) + 4 * h;
        yb[q5 * YPAD + o] = yt[reg];
    }
    __syncthreads();
    {
        int qq = lane >> 1, half = lane & 1;
        const float* src = yb + qq * YPAD + half * 16;
        float4 s0 = *(const float4*)(src);
        float4 s1 = *(const float4*)(src + 4);
        float4 s2 = *(const float4*)(src + 8);
        float4 s3 = *(const float4*)(src + 12);
        ushort8v pk0, pk1;
        pk0[0] = f2bf_rne(s0.x); pk0[1] = f2bf_rne(s0.y);
        pk0[2] = f2bf_rne(s0.z); pk0[3] = f2bf_rne(s0.w);
        pk0[4] = f2bf_rne(s1.x); pk0[5] = f2bf_rne(s1.y);
        pk0[6] = f2bf_rne(s1.z); pk0[7] = f2bf_rne(s1.w);
        pk1[0] = f2bf_rne(s2.x); pk1[1] = f2bf_rne(s2.y);
        pk1[2] = f2bf_rne(s2.z); pk1[3] = f2bf_rne(s2.w);
        pk1[4] = f2bf_rne(s3.x); pk1[5] = f2bf_rne(s3.y);
        pk1[6] = f2bf_rne(s3.z); pk1[7] = f2bf_rne(s3.w);
        ushort_t* dst = py + ((size_t)sp * BN + (size_t)b * NN + n0 + qq) * CH2 + half * 16;
        *(ushort8v*)(dst)     = pk0;
        *(ushort8v*)(dst + 8) = pk1;
    }
    // l: every lt row holds the full key-sum for column q5
    if (h == 0) pl[(size_t)sp * BN + (size_t)b * NN + n0 + q5] = lt[0];
}

// ---- reduce+proj: two-phase, MFMA projection.
// R9: supports up to 8 splits, all partial loads unrolled & in flight.
__global__ __launch_bounds__(256) void reduce_proj(const ushort_t* __restrict__ py,
                                                   const float* __restrict__ pl,
                                                   const float* __restrict__ Ww,
                                                   const float* __restrict__ Wb,
                                                   const float* __restrict__ x,
                                                   float* __restrict__ out,
                                                   int nsplit) {
    __shared__ ushort_t WwB[CH * RPAD];
    __shared__ ushort_t Y[64 * RPAD];
    __shared__ float    linv[64];
    __shared__ float    WbL[CH];

    const int t = threadIdx.x;
    const int row = t >> 2, o8 = (t & 3) * 8;
    const int grow0 = blockIdx.x * 64;

    {
        const float* wp = Ww + row * CH2 + o8;
        ushort8v w;
        #pragma unroll
        for (int j = 0; j < 8; ++j) w[j] = f2bf_rne(wp[j]);
        *(ushort8v*)(&WwB[row * RPAD + o8]) = w;
    }
    if (t < CH) WbL[t] = Wb[t];
    if (t < 64) {
        const float* plp = pl + grow0 + t;
        float lv[MAXSPLIT];
        #pragma unroll
        for (int s = 0; s < MAXSPLIT; ++s) {
            int sc = s < nsplit ? s : 0;
            lv[s] = plp[(size_t)sc * BN];
        }
        float l = 0.f;
        #pragma unroll
        for (int s = 0; s < MAXSPLIT; ++s) if (s < nsplit) l += lv[s];
        linv[t] = 1.0f / l;
    }

    float acc[8];
    #pragma unroll
    for (int j = 0; j < 8; ++j) acc[j] = 0.f;
    {
        const ushort_t* pp = py + ((size_t)(grow0 + row)) * CH2 + o8;
        ushort8v pv[MAXSPLIT];
        #pragma unroll
        for (int s = 0; s < MAXSPLIT; ++s) {
            int sc = s < nsplit ? s : 0;
            pv[s] = *(const ushort8v*)(pp + (size_t)sc * BN * CH2);
        }
        #pragma unroll
        for (int s = 0; s < MAXSPLIT; ++s) if (s < nsplit) {
            #pragma unroll
            for (int j = 0; j < 8; ++j)
                acc[j] += __uint_as_float((unsigned int)pv[s][j] << 16);
        }
    }
    __syncthreads();
    {
        float inv = linv[row];
        ushort8v yv;
        #pragma unroll
        for (int j = 0; j < 8; ++j) yv[j] = f2bf_rne(acc[j] * inv);
        *(ushort8v*)(&Y[row * RPAD + o8]) = yv;
    }
    __syncthreads();

    const int wave = t >> 6, lane = t & 63;
    const int ql = lane & 15, quad = lane >> 4;
    const int b = grow0 >> 12;
    const int nbase = (grow0 & (NN - 1)) + wave * 16;

    short8 bfrag = *(const short8*)(&Y[(wave * 16 + ql) * RPAD + quad * 8]);
    #pragma unroll
    for (int ct = 0; ct < 4; ++ct) {
        short8 afrag = *(const short8*)(&WwB[(ct * 16 + ql) * RPAD + quad * 8]);
        floatx4 d = (floatx4){0.f, 0.f, 0.f, 0.f};
        d = __builtin_amdgcn_mfma_f32_16x16x32_bf16(afrag, bfrag, d, 0, 0, 0);
        #pragma unroll
        for (int r = 0; r < 4; ++r) {
            int c = ct * 16 + quad * 4 + r;
            size_t oi = ((size_t)b * CH + c) * NN + nbase + ql;
            out[oi] = d[r] + WbL[c] + x[oi];
        }
    }
}

extern "C" void kernel_launch(void* const* d_in, const int* in_sizes, int n_in,
                              void* d_out, int out_size, void* d_ws, size_t ws_size,
                              hipStream_t stream) {
    const float* x  = (const float*)d_in[0];
    const float* gw = (const float*)d_in[1];
    const float* gb = (const float*)d_in[2];
    const float* Ww = (const float*)d_in[3];
    const float* Wb = (const float*)d_in[4];
    float* out = (float*)d_out;

    ushort_t* xT   = (ushort_t*)d_ws;                          // 4 MB
    ushort_t* gxT  = xT + (size_t)BN * CH;                     // 2 MB
    float*    mlog = (float*)(gxT + (size_t)BATCH * CH2 * NN); // 128 KB
    ushort_t* py   = (ushort_t*)(mlog + BN);                   // split*BN*32 bf16
    size_t base_bytes = (size_t)BN * CH * 2 + (size_t)BATCH * CH2 * NN * 2 + (size_t)BN * 4;
    int split = MAXSPLIT;
    while (split > 1 && base_bytes + (size_t)split * BN * (CH2 * 2 + 4) > ws_size)
        split >>= 1;
    float* pl = (float*)(py + (size_t)split * BN * CH2);

    hipLaunchKernelGGL(prep_fused,  dim3(BN * 4 / 256), dim3(256), 0, stream,
                       x, gw, gb, xT, mlog, gxT);
    hipLaunchKernelGGL(flash_attn,  dim3(256 * split),  dim3(256), 0, stream,
                       xT, gxT, mlog, py, pl, NN / split);
    hipLaunchKernelGGL(reduce_proj, dim3(BN / 64),      dim3(256), 0, stream,
                       py, pl, Ww, Wb, x, out, split);
}

// Round 3
// 111.988 us; speedup vs baseline: 5.0057x; 5.0057x over previous
//
#include <hip/hip_runtime.h>
#include <hip/hip_bf16.h>

#define BATCH 8
#define CH    64
#define CH2   32
#define NN    4096
#define BN    (BATCH * NN)   // 32768 rows total
#define KPAD  72             // LDS key-tile row stride (elements)
#define VPAD  72             // LDS value-tile row stride (elements)
#define YPAD  36             // flash epilogue transpose row stride (floats)
#define RPAD  40             // reduce_proj LDS row stride (bf16 elements, 16B-aligned)
#define MAXSPLIT 8

typedef __attribute__((ext_vector_type(8)))  short        short8;    // 8 bf16 (MFMA A/B frag)
typedef __attribute__((ext_vector_type(4)))  float        floatx4;   // 16x16 MFMA C/D frag
typedef __attribute__((ext_vector_type(16))) float        floatx16;  // 32x32 MFMA C/D frag
typedef __attribute__((ext_vector_type(4)))  unsigned int uint4v;
typedef __attribute__((ext_vector_type(8)))  unsigned short ushort8v;
typedef unsigned short ushort_t;

#define LOG2E      1.4426950408889634f
#define SQRT_LOG2E 1.2011224087864498f   // sqrt(log2(e)); Q,K both scaled -> S in log2 units

__device__ __forceinline__ unsigned short f2bf_rne(float f) {
    unsigned int u = __float_as_uint(f);
    return (unsigned short)((u + 0x7FFFu + ((u >> 16) & 1u)) >> 16);
}

// ---- fused prep (unchanged)
__global__ __launch_bounds__(256) void prep_fused(const float* __restrict__ x,
                                                  const float* __restrict__ gw,
                                                  const float* __restrict__ gb,
                                                  ushort_t* __restrict__ xT,
                                                  float* __restrict__ mlog,
                                                  ushort_t* __restrict__ gxT) {
    __shared__ float gwl[CH2 * CH];   // [o][c]
    __shared__ float gbl[CH2];
    int t = threadIdx.x;
    for (int i = t; i < CH2 * CH; i += 256) gwl[i] = gw[i];
    if (t < CH2) gbl[t] = gb[t];
    __syncthreads();

    int g   = blockIdx.x * 256 + t;
    int row = g >> 2;
    int q4  = g & 3;
    int b = row >> 12, n = row & (NN - 1);
    const float* xp = x + (size_t)b * CH * NN + n;

    float xv[16];
    #pragma unroll
    for (int j = 0; j < 16; ++j) xv[j] = xp[(size_t)(q4 * 16 + j) * NN];

    float ns = 0.f;
    short8 v0, v1;
    #pragma unroll
    for (int j = 0; j < 8; ++j) {
        ns += xv[j] * xv[j];
        v0[j] = (short)f2bf_rne(xv[j] * SQRT_LOG2E);
    }
    #pragma unroll
    for (int j = 0; j < 8; ++j) {
        ns += xv[8 + j] * xv[8 + j];
        v1[j] = (short)f2bf_rne(xv[8 + j] * SQRT_LOG2E);
    }
    *(short8*)(xT + (size_t)row * CH + q4 * 16)     = v0;
    *(short8*)(xT + (size_t)row * CH + q4 * 16 + 8) = v1;
    ns += __shfl_xor(ns, 1);
    ns += __shfl_xor(ns, 2);
    if (q4 == 0) mlog[row] = 12.0f * sqrtf(ns) * LOG2E;

    float acc[CH2];
    #pragma unroll
    for (int o = 0; o < CH2; ++o) {
        const float4* wr = (const float4*)(gwl + o * CH + q4 * 16);
        float4 w0 = wr[0], w1 = wr[1], w2 = wr[2], w3 = wr[3];
        float a;
        a  = w0.x * xv[0]  + w0.y * xv[1]  + w0.z * xv[2]  + w0.w * xv[3];
        a += w1.x * xv[4]  + w1.y * xv[5]  + w1.z * xv[6]  + w1.w * xv[7];
        a += w2.x * xv[8]  + w2.y * xv[9]  + w2.z * xv[10] + w2.w * xv[11];
        a += w3.x * xv[12] + w3.y * xv[13] + w3.z * xv[14] + w3.w * xv[15];
        acc[o] = a;
    }
    #pragma unroll
    for (int o = 0; o < CH2; ++o) {
        acc[o] += __shfl_xor(acc[o], 1);
        acc[o] += __shfl_xor(acc[o], 2);
    }
    #pragma unroll
    for (int i = 0; i < 8; ++i) {
        int o = q4 * 8 + i;
        gxT[((size_t)b * CH2 + o) * NN + n] = f2bf_rne(acc[o] + gbl[o]);
    }
}

// ---- flash attention, S^T formulation (32x32x16 MFMA).
// R10: register-footprint attack at fixed (256,4) bound (R9's (256,8) caused a
// spill catastrophe: 2.3 GB scratch traffic).
//  - l accumulated as scalar f32 from the already-computed exp2 values
//    (removes the 4 ones-MFMAs per tile = 25% of MFMA work, frees lt+ones regs)
//  - per-subtile softmax shift via MFMA C!=D: persistent mlC fragment is the C
//    operand of the first QK MFMA (removes 32 v_mov per tile)
//  - split=8 (grid 2048) for load balance; no reg prefetch (neutral in R8/R9,
//    costs 24 live VGPRs)
__global__ __launch_bounds__(256, 4) void flash_attn(const ushort_t* __restrict__ xT,
                                                     const ushort_t* __restrict__ gxT,
                                                     const float* __restrict__ mlog,
                                                     ushort_t* __restrict__ py,
                                                     float* __restrict__ pl,
                                                     int ksplit) {
    __shared__ __align__(16) unsigned char smem[18432];
    ushort_t* Klds = (ushort_t*)smem;               // 64 x KPAD bf16 (9216 B)
    ushort_t* Vlds = Klds + 64 * KPAD;              // 32 x VPAD bf16 (4608 B)

    const int tid = threadIdx.x, wave = tid >> 6, lane = tid & 63;
    const int q5 = lane & 31;
    const int h  = lane >> 5;
    const int bq = blockIdx.x & 255;
    const int sp = blockIdx.x >> 8;
    const int b = bq >> 5, qt = bq & 31;
    const int n0 = qt * 128 + wave * 32;
    const int k0 = sp * ksplit;

    short8 qf[4];
    {
        const ushort_t* qp = xT + ((size_t)(b * NN + n0 + q5)) * CH + h * 8;
        #pragma unroll
        for (int f = 0; f < 4; ++f) qf[f] = *(const short8*)(qp + f * 16);
    }
    const float ml = mlog[(size_t)b * NN + n0 + q5];

    floatx16 mlC;                         // persistent C operand: softmax shift
    #pragma unroll
    for (int i = 0; i < 16; ++i) mlC[i] = -ml;

    floatx16 yt;
    #pragma unroll
    for (int i = 0; i < 16; ++i) yt[i] = 0.f;
    float lsum = 0.f;

    const ushort_t* kb = xT + (size_t)(b * NN + k0) * CH;
    const ushort_t* vb = gxT + (size_t)b * CH2 * NN + k0;
    const int iters = ksplit >> 6;
    const int skey = tid >> 3, sc0 = (tid & 7) * 8;   // K rows 0..31(+32), V och 0..31

    for (int kt = 0; kt < iters; ++kt) {
        const size_t kof = (size_t)kt << 12;
        short8 gk0 = *(const short8*)(kb + kof + (size_t)skey * CH + sc0);
        short8 gk1 = *(const short8*)(kb + kof + (size_t)(skey + 32) * CH + sc0);
        short8 gv  = *(const short8*)(vb + (size_t)skey * NN + kt * 64 + sc0);

        __syncthreads();                  // prior tile's reads complete
        *(short8*)(&Klds[skey * KPAD + sc0])        = gk0;
        *(short8*)(&Klds[(skey + 32) * KPAD + sc0]) = gk1;
        *(short8*)(&Vlds[skey * VPAD + sc0])        = gv;
        __syncthreads();                  // publish tile kt

        short8 vf[4];
        #pragma unroll
        for (int fr = 0; fr < 4; ++fr)
            vf[fr] = *(const short8*)(&Vlds[q5 * VPAD + fr * 16 + h * 8]);

        #pragma unroll
        for (int T = 0; T < 2; ++T) {
            floatx16 st;
            __builtin_amdgcn_s_setprio(1);
            {
                short8 kf = *(const short8*)(&Klds[(T * 32 + q5) * KPAD + h * 8]);
                st = __builtin_amdgcn_mfma_f32_32x32x16_bf16(kf, qf[0], mlC, 0, 0, 0);
            }
            #pragma unroll
            for (int f = 1; f < 4; ++f) {
                short8 kf = *(const short8*)(&Klds[(T * 32 + q5) * KPAD + f * 16 + h * 8]);
                st = __builtin_amdgcn_mfma_f32_32x32x16_bf16(kf, qf[f], st, 0, 0, 0);
            }
            __builtin_amdgcn_s_setprio(0);
            // P = exp2(st); accumulate l in f32; pack pairs to bf16 (RNE) 1 op each
            unsigned int d[8];
            #pragma unroll
            for (int r2 = 0; r2 < 8; ++r2) {
                float p0 = __builtin_amdgcn_exp2f(st[2 * r2]);
                float p1 = __builtin_amdgcn_exp2f(st[2 * r2 + 1]);
                lsum += p0;
                lsum += p1;
                unsigned int pk;
                asm("v_cvt_pk_bf16_f32 %0, %1, %2" : "=v"(pk) : "v"(p0), "v"(p1));
                d[r2] = pk;
            }
            // P^T B-frags: lane^32 exchange via permlane32_swap
            #pragma unroll
            for (int fp = 0; fp < 2; ++fp) {
                unsigned int b0 = d[fp * 4 + 0], b1 = d[fp * 4 + 1];
                unsigned int b2 = d[fp * 4 + 2], b3 = d[fp * 4 + 3];
                asm("v_permlane32_swap_b32 %0, %1" : "+v"(b0), "+v"(b2));
                asm("v_permlane32_swap_b32 %0, %1" : "+v"(b1), "+v"(b3));
                uint4v bv;
                bv[0] = b0; bv[1] = b1; bv[2] = b2; bv[3] = b3;
                short8 pb = __builtin_bit_cast(short8, bv);
                __builtin_amdgcn_s_setprio(1);
                yt = __builtin_amdgcn_mfma_f32_32x32x16_bf16(vf[T * 2 + fp], pb, yt, 0, 0, 0);
                __builtin_amdgcn_s_setprio(0);
            }
        }
    }

    // fold the two key-halves of lsum (each lane summed 16 of 32 rows per subtile)
    lsum += __shfl_xor(lsum, 32);

    // epilogue: transpose y^T via LDS (aliases K/V buffer; drain reads first)
    __syncthreads();
    float* yb = (float*)smem + wave * 32 * YPAD;
    #pragma unroll
    for (int reg = 0; reg < 16; ++reg) {
        int o = (reg & 3) + 8 * (reg >> 2) + 4 * h;
        yb[q5 * YPAD + o] = yt[reg];
    }
    __syncthreads();
    {
        int qq = lane >> 1, half = lane & 1;
        const float* src = yb + qq * YPAD + half * 16;
        float4 s0 = *(const float4*)(src);
        float4 s1 = *(const float4*)(src + 4);
        float4 s2 = *(const float4*)(src + 8);
        float4 s3 = *(const float4*)(src + 12);
        ushort8v pk0, pk1;
        pk0[0] = f2bf_rne(s0.x); pk0[1] = f2bf_rne(s0.y);
        pk0[2] = f2bf_rne(s0.z); pk0[3] = f2bf_rne(s0.w);
        pk0[4] = f2bf_rne(s1.x); pk0[5] = f2bf_rne(s1.y);
        pk0[6] = f2bf_rne(s1.z); pk0[7] = f2bf_rne(s1.w);
        pk1[0] = f2bf_rne(s2.x); pk1[1] = f2bf_rne(s2.y);
        pk1[2] = f2bf_rne(s2.z); pk1[3] = f2bf_rne(s2.w);
        pk1[4] = f2bf_rne(s3.x); pk1[5] = f2bf_rne(s3.y);
        pk1[6] = f2bf_rne(s3.z); pk1[7] = f2bf_rne(s3.w);
        ushort_t* dst = py + ((size_t)sp * BN + (size_t)b * NN + n0 + qq) * CH2 + half * 16;
        *(ushort8v*)(dst)     = pk0;
        *(ushort8v*)(dst + 8) = pk1;
    }
    if (h == 0) pl[(size_t)sp * BN + (size_t)b * NN + n0 + q5] = lsum;
}

// ---- reduce+proj: two-phase, MFMA projection; up to 8 partials in flight.
__global__ __launch_bounds__(256) void reduce_proj(const ushort_t* __restrict__ py,
                                                   const float* __restrict__ pl,
                                                   const float* __restrict__ Ww,
                                                   const float* __restrict__ Wb,
                                                   const float* __restrict__ x,
                                                   float* __restrict__ out,
                                                   int nsplit) {
    __shared__ ushort_t WwB[CH * RPAD];
    __shared__ ushort_t Y[64 * RPAD];
    __shared__ float    linv[64];
    __shared__ float    WbL[CH];

    const int t = threadIdx.x;
    const int row = t >> 2, o8 = (t & 3) * 8;
    const int grow0 = blockIdx.x * 64;

    {
        const float* wp = Ww + row * CH2 + o8;
        ushort8v w;
        #pragma unroll
        for (int j = 0; j < 8; ++j) w[j] = f2bf_rne(wp[j]);
        *(ushort8v*)(&WwB[row * RPAD + o8]) = w;
    }
    if (t < CH) WbL[t] = Wb[t];
    if (t < 64) {
        const float* plp = pl + grow0 + t;
        float lv[MAXSPLIT];
        #pragma unroll
        for (int s = 0; s < MAXSPLIT; ++s) {
            int sc = s < nsplit ? s : 0;
            lv[s] = plp[(size_t)sc * BN];
        }
        float l = 0.f;
        #pragma unroll
        for (int s = 0; s < MAXSPLIT; ++s) if (s < nsplit) l += lv[s];
        linv[t] = 1.0f / l;
    }

    float acc[8];
    #pragma unroll
    for (int j = 0; j < 8; ++j) acc[j] = 0.f;
    {
        const ushort_t* pp = py + ((size_t)(grow0 + row)) * CH2 + o8;
        ushort8v pv[MAXSPLIT];
        #pragma unroll
        for (int s = 0; s < MAXSPLIT; ++s) {
            int sc = s < nsplit ? s : 0;
            pv[s] = *(const ushort8v*)(pp + (size_t)sc * BN * CH2);
        }
        #pragma unroll
        for (int s = 0; s < MAXSPLIT; ++s) if (s < nsplit) {
            #pragma unroll
            for (int j = 0; j < 8; ++j)
                acc[j] += __uint_as_float((unsigned int)pv[s][j] << 16);
        }
    }
    __syncthreads();
    {
        float inv = linv[row];
        ushort8v yv;
        #pragma unroll
        for (int j = 0; j < 8; ++j) yv[j] = f2bf_rne(acc[j] * inv);
        *(ushort8v*)(&Y[row * RPAD + o8]) = yv;
    }
    __syncthreads();

    const int wave = t >> 6, lane = t & 63;
    const int ql = lane & 15, quad = lane >> 4;
    const int b = grow0 >> 12;
    const int nbase = (grow0 & (NN - 1)) + wave * 16;

    short8 bfrag = *(const short8*)(&Y[(wave * 16 + ql) * RPAD + quad * 8]);
    #pragma unroll
    for (int ct = 0; ct < 4; ++ct) {
        short8 afrag = *(const short8*)(&WwB[(ct * 16 + ql) * RPAD + quad * 8]);
        floatx4 d = (floatx4){0.f, 0.f, 0.f, 0.f};
        d = __builtin_amdgcn_mfma_f32_16x16x32_bf16(afrag, bfrag, d, 0, 0, 0);
        #pragma unroll
        for (int r = 0; r < 4; ++r) {
            int c = ct * 16 + quad * 4 + r;
            size_t oi = ((size_t)b * CH + c) * NN + nbase + ql;
            out[oi] = d[r] + WbL[c] + x[oi];
        }
    }
}

extern "C" void kernel_launch(void* const* d_in, const int* in_sizes, int n_in,
                              void* d_out, int out_size, void* d_ws, size_t ws_size,
                              hipStream_t stream) {
    const float* x  = (const float*)d_in[0];
    const float* gw = (const float*)d_in[1];
    const float* gb = (const float*)d_in[2];
    const float* Ww = (const float*)d_in[3];
    const float* Wb = (const float*)d_in[4];
    float* out = (float*)d_out;

    ushort_t* xT   = (ushort_t*)d_ws;                          // 4 MB
    ushort_t* gxT  = xT + (size_t)BN * CH;                     // 2 MB
    float*    mlog = (float*)(gxT + (size_t)BATCH * CH2 * NN); // 128 KB
    ushort_t* py   = (ushort_t*)(mlog + BN);                   // split*BN*32 bf16
    size_t base_bytes = (size_t)BN * CH * 2 + (size_t)BATCH * CH2 * NN * 2 + (size_t)BN * 4;
    int split = MAXSPLIT;
    while (split > 1 && base_bytes + (size_t)split * BN * (CH2 * 2 + 4) > ws_size)
        split >>= 1;
    float* pl = (float*)(py + (size_t)split * BN * CH2);

    hipLaunchKernelGGL(prep_fused,  dim3(BN * 4 / 256), dim3(256), 0, stream,
                       x, gw, gb, xT, mlog, gxT);
    hipLaunchKernelGGL(flash_attn,  dim3(256 * split),  dim3(256), 0, stream,
                       xT, gxT, mlog, py, pl, NN / split);
    hipLaunchKernelGGL(reduce_proj, dim3(BN / 64),      dim3(256), 0, stream,
                       py, pl, Ww, Wb, x, out, split);
}